// Round 1
// baseline (280.351 us; speedup 1.0000x reference)
//
#include <hip/hip_runtime.h>
#include <cstdint>
#include <cstddef>

#define B_DIM 8
#define L_DIM 33600
#define N_DIM 128
#define C_DIM 80
#define K_TOP 13
#define EPS_F 1e-9f

// Bit-exact replica of the reference IoU (f32, no FMA contraction, same op order):
// lt=max, rb=min, wh=clip(rb-lt,0), inter=wx*wy, areas, den=((ag+ap)-inter)+EPS,
// iou=inter/den, where(iou>1+EPS -> 1.0f in f32, 0), clip to [0,1].
__device__ __forceinline__ float iou_pair(float g0, float g1, float g2, float g3,
                                          float p0, float p1, float p2, float p3) {
    float ltx = fmaxf(g0, p0), lty = fmaxf(g1, p1);
    float rbx = fminf(g2, p2), rby = fminf(g3, p3);
    float wx = fmaxf(__fsub_rn(rbx, ltx), 0.0f);
    float wy = fmaxf(__fsub_rn(rby, lty), 0.0f);
    float inter = __fmul_rn(wx, wy);
    float ag = __fmul_rn(__fsub_rn(g2, g0), __fsub_rn(g3, g1));
    float ap = __fmul_rn(__fsub_rn(p2, p0), __fsub_rn(p3, p1));
    float den = __fadd_rn(__fsub_rn(__fadd_rn(ag, ap), inter), EPS_F);
    float iou = __fdiv_rn(inter, den);
    if (iou > 1.0f) iou = 0.0f;            // (1.0 + 1e-9) rounds to 1.0f in f32
    iou = fminf(fmaxf(iou, 0.0f), 1.0f);
    return iou;
}

// K1: one block per (gt n, batch b). Scan all L anchors, keep top-13 of
// s = spatial ? cs * iou^6 : 0 with jax.lax.top_k tie semantics
// (value desc, index asc; zeros are candidates). Scatter winner bits.
__global__ __launch_bounds__(256) void k_topk(
    const float* __restrict__ psc, const float* __restrict__ pbox,
    const float* __restrict__ pts, const int* __restrict__ glbl,
    const float* __restrict__ gbox, const float* __restrict__ gpad,
    unsigned long long* __restrict__ posbits)
{
    const int n = blockIdx.x, b = blockIdx.y, t = threadIdx.x;
    if (gpad[b * N_DIM + n] <= 0.0f) return;   // padded GT: no picks (uniform exit)

    const float g0 = gbox[(b * N_DIM + n) * 4 + 0];
    const float g1 = gbox[(b * N_DIM + n) * 4 + 1];
    const float g2 = gbox[(b * N_DIM + n) * 4 + 2];
    const float g3 = gbox[(b * N_DIM + n) * 4 + 3];
    int lbl = glbl[b * N_DIM + n];
    lbl = min(max(lbl, 0), C_DIM - 1);
    const float* psb = psc + (size_t)b * L_DIM * C_DIM;
    const float* pbb = pbox + (size_t)b * L_DIM * 4;

    double tv[K_TOP]; int ti[K_TOP];
    #pragma unroll
    for (int k = 0; k < K_TOP; ++k) { tv[k] = -1.0; ti[k] = 0x7fffffff; }
    double worstV = -1.0; int worstI = 0x7fffffff;   // guard in registers

    for (int l = t; l < L_DIM; l += 256) {
        const float2 ap = reinterpret_cast<const float2*>(pts)[l];
        double s = 0.0;
        if (ap.x >= g0 && ap.x <= g2 && ap.y >= g1 && ap.y <= g3) {
            const float4 pbv = reinterpret_cast<const float4*>(pbb)[l];
            float iou = iou_pair(g0, g1, g2, g3, pbv.x, pbv.y, pbv.z, pbv.w);
            if (iou > 0.0f) {
                float cs = psb[(size_t)l * C_DIM + lbl];
                double d = (double)iou, d2 = d * d;
                s = (double)cs * (d2 * d2 * d2);   // exact-ish true value ranking
            }
        }
        if (s > worstV || (s == worstV && l < worstI)) {
            int p = K_TOP - 1;
            while (p > 0 && (s > tv[p - 1] || (s == tv[p - 1] && l < ti[p - 1]))) {
                tv[p] = tv[p - 1]; ti[p] = ti[p - 1]; --p;
            }
            tv[p] = s; ti[p] = l;
            worstV = tv[K_TOP - 1]; worstI = ti[K_TOP - 1];
        }
    }

    __shared__ double cv[256 * K_TOP];
    __shared__ int    ci[256 * K_TOP];
    __shared__ double rv[256];
    __shared__ int    ri[256];
    __shared__ int    rp[256];
    #pragma unroll
    for (int k = 0; k < K_TOP; ++k) { cv[t * K_TOP + k] = tv[k]; ci[t * K_TOP + k] = ti[k]; }
    __syncthreads();

    for (int r = 0; r < K_TOP; ++r) {
        double bv = -2.0; int bi = 0x7fffffff, bp = 0;
        #pragma unroll
        for (int k = 0; k < K_TOP; ++k) {
            double v = cv[t * K_TOP + k]; int i = ci[t * K_TOP + k];
            if (v > bv || (v == bv && i < bi)) { bv = v; bi = i; bp = t * K_TOP + k; }
        }
        rv[t] = bv; ri[t] = bi; rp[t] = bp;
        __syncthreads();
        for (int s2 = 128; s2 > 0; s2 >>= 1) {
            if (t < s2) {
                if (rv[t + s2] > rv[t] || (rv[t + s2] == rv[t] && ri[t + s2] < ri[t])) {
                    rv[t] = rv[t + s2]; ri[t] = ri[t + s2]; rp[t] = rp[t + s2];
                }
            }
            __syncthreads();
        }
        if (t == 0) {
            int win = ri[0];
            cv[rp[0]] = -2.0;   // remove winner; always >=13 real candidates remain
            atomicOr(&posbits[((size_t)b * L_DIM + win) * 2 + (n >> 6)],
                     1ULL << (n & 63));
        }
        __syncthreads();
    }
}

// K2: one thread per anchor. Recompute 128 ious (GT boxes in LDS), build
// positive = topk_bit & spatial, resolve conflicts via best-iou argmax
// (first-max semantics), write labels/boxes, feed per-GT maxima atomics.
__global__ __launch_bounds__(256) void k_assign(
    const float* __restrict__ psc, const float* __restrict__ pbox,
    const float* __restrict__ pts, const int* __restrict__ glbl,
    const float* __restrict__ gbox,
    const unsigned long long* __restrict__ posbits,
    const int* __restrict__ bgp,
    float* __restrict__ out_lab, float* __restrict__ out_box,
    int* __restrict__ fin_out, float* __restrict__ alat,
    float* __restrict__ maxal, float* __restrict__ maxio)
{
    const int b = blockIdx.y, t = threadIdx.x;
    const int l = blockIdx.x * 256 + t;
    __shared__ float4 gb[N_DIM];
    __shared__ int    gl[N_DIM];
    if (t < N_DIM) {
        gb[t] = reinterpret_cast<const float4*>(gbox)[(size_t)b * N_DIM + t];
        gl[t] = glbl[b * N_DIM + t];
    }
    __syncthreads();
    if (l >= L_DIM) return;

    const size_t bl = (size_t)b * L_DIM + l;
    const float4 pb = reinterpret_cast<const float4*>(pbox)[bl];
    const float2 ap = reinterpret_cast<const float2*>(pts)[l];
    const unsigned long long w0 = posbits[bl * 2 + 0];
    const unsigned long long w1 = posbits[bl * 2 + 1];

    unsigned long long s0 = 0ull, s1 = 0ull;
    float best = -1.0f; int bestn = 0;
    for (int n = 0; n < N_DIM; ++n) {
        float4 g = gb[n];
        float iou = iou_pair(g.x, g.y, g.z, g.w, pb.x, pb.y, pb.z, pb.w);
        if (iou > best) { best = iou; bestn = n; }            // strict > = first-max
        if (ap.x >= g.x && ap.x <= g.z && ap.y >= g.y && ap.y <= g.w) {
            if (n < 64) s0 |= 1ull << n; else s1 |= 1ull << (n - 64);
        }
    }
    unsigned long long p0 = w0 & s0, p1 = w1 & s1;
    int cnt = __popcll(p0) + __popcll(p1);
    int fin;
    if (cnt == 0) fin = -1;
    else if (cnt == 1) fin = p0 ? (__ffsll(p0) - 1) : (64 + __ffsll(p1) - 1);
    else {
        bool posbest = (bestn < 64) ? ((p0 >> bestn) & 1ull) : ((p1 >> (bestn - 64)) & 1ull);
        fin = posbest ? bestn : -1;
    }

    out_lab[bl] = (fin >= 0) ? (float)gl[fin] : (float)bgp[0];
    int gidx = (fin >= 0) ? fin : 0;              // ref gathers boxes with argmax=0 for bg
    reinterpret_cast<float4*>(out_box)[bl] = gb[gidx];
    fin_out[bl] = fin;

    if (fin >= 0) {
        float4 g = gb[fin];
        float iou = iou_pair(g.x, g.y, g.z, g.w, pb.x, pb.y, pb.z, pb.w);
        int lb = min(max(gl[fin], 0), C_DIM - 1);
        float cs = psc[bl * C_DIM + lb];
        float al = cs * powf(iou, 6.0f);
        alat[bl] = al;
        // all values >= 0, init 0 -> int-compare == float-compare
        atomicMax((int*)&maxal[b * N_DIM + fin], __float_as_int(al));
        atomicMax((int*)&maxio[b * N_DIM + fin], __float_as_int(iou));
    }
}

// K3a: per-anchor norm factor + assigned class (-1 = background).
__global__ __launch_bounds__(256) void k_norm(
    const int* __restrict__ fin_out, const float* __restrict__ alat,
    const float* __restrict__ maxal, const float* __restrict__ maxio,
    const int* __restrict__ glbl,
    float* __restrict__ nf, int* __restrict__ cls)
{
    int i = blockIdx.x * 256 + threadIdx.x;
    if (i >= B_DIM * L_DIM) return;
    int b = i / L_DIM;
    int fin = fin_out[i];
    float v = 0.0f; int c = -1;
    if (fin >= 0) {
        v = alat[i] / (maxal[b * N_DIM + fin] + EPS_F) * maxio[b * N_DIM + fin];
        c = glbl[b * N_DIM + fin];
    }
    nf[i] = v; cls[i] = c;
}

// K3: fill the one-hot-scaled scores, float4-vectorized (C=80 divisible by 4).
__global__ __launch_bounds__(256) void k_scores(
    const float* __restrict__ nf, const int* __restrict__ cls,
    float* __restrict__ outs)
{
    const int TOT4 = B_DIM * L_DIM * C_DIM / 4;
    int q = blockIdx.x * 256 + threadIdx.x;
    if (q >= TOT4) return;
    int idx = q * 4;
    int a = idx / C_DIM;
    int c0 = idx - a * C_DIM;
    int cl = cls[a];
    float v = nf[a];
    float4 o;
    o.x = (c0 + 0 == cl) ? v : 0.0f;
    o.y = (c0 + 1 == cl) ? v : 0.0f;
    o.z = (c0 + 2 == cl) ? v : 0.0f;
    o.w = (c0 + 3 == cl) ? v : 0.0f;
    reinterpret_cast<float4*>(outs)[q] = o;
}

extern "C" void kernel_launch(void* const* d_in, const int* in_sizes, int n_in,
                              void* d_out, int out_size, void* d_ws, size_t ws_size,
                              hipStream_t stream)
{
    const float* psc  = (const float*)d_in[0];   // [B,L,C]
    const float* pbox = (const float*)d_in[1];   // [B,L,4]
    const float* pts  = (const float*)d_in[2];   // [1,L,2]
    const int*   glbl = (const int*)d_in[3];     // [B,N,1]
    const float* gbox = (const float*)d_in[4];   // [B,N,4]
    const float* gpad = (const float*)d_in[5];   // [B,N,1]
    const int*   bgp  = (const int*)d_in[6];     // scalar (=C)

    // workspace layout (8-byte aligned blocks)
    const size_t POSB_BYTES = (size_t)B_DIM * L_DIM * 2 * sizeof(unsigned long long); // 4,300,800
    char* w = (char*)d_ws;
    unsigned long long* posbits = (unsigned long long*)w;
    float* maxal = (float*)(w + POSB_BYTES);                                   // 4096 B
    float* maxio = (float*)(w + POSB_BYTES + 4096);                            // 4096 B
    int*   fin   = (int*)  (w + POSB_BYTES + 8192);                            // 1,075,200 B
    float* alat  = (float*)(w + POSB_BYTES + 8192 + 1075200);
    float* nf    = (float*)(w + POSB_BYTES + 8192 + 2 * 1075200);
    int*   cls   = (int*)  (w + POSB_BYTES + 8192 + 3 * 1075200);

    // zero the accumulated regions (posbits + maxal + maxio) every call
    hipMemsetAsync(d_ws, 0, POSB_BYTES + 8192, stream);

    float* out_lab = (float*)d_out;                              // [B,L]
    float* out_box = out_lab + (size_t)B_DIM * L_DIM;            // [B,L,4]
    float* out_sc  = out_box + (size_t)B_DIM * L_DIM * 4;        // [B,L,C]

    dim3 blk(256);
    k_topk<<<dim3(N_DIM, B_DIM), blk, 0, stream>>>(psc, pbox, pts, glbl, gbox, gpad, posbits);
    k_assign<<<dim3((L_DIM + 255) / 256, B_DIM), blk, 0, stream>>>(
        psc, pbox, pts, glbl, gbox, posbits, bgp,
        out_lab, out_box, fin, alat, maxal, maxio);
    k_norm<<<dim3((B_DIM * L_DIM + 255) / 256), blk, 0, stream>>>(
        fin, alat, maxal, maxio, glbl, nf, cls);
    k_scores<<<dim3((B_DIM * L_DIM * C_DIM / 4 + 255) / 256), blk, 0, stream>>>(
        nf, cls, out_sc);
}

// Round 2
// 220.502 us; speedup vs baseline: 1.2714x; 1.2714x over previous
//
#include <hip/hip_runtime.h>
#include <cstdint>
#include <cstddef>

#define B_DIM 8
#define L_DIM 33600
#define N_DIM 128
#define C_DIM 80
#define K_TOP 13
#define EPS_F 1e-9f

// Bit-exact replica of the reference IoU (f32, no FMA contraction, same op order).
__device__ __forceinline__ float iou_pair(float g0, float g1, float g2, float g3,
                                          float p0, float p1, float p2, float p3) {
    float ltx = fmaxf(g0, p0), lty = fmaxf(g1, p1);
    float rbx = fminf(g2, p2), rby = fminf(g3, p3);
    float wx = fmaxf(__fsub_rn(rbx, ltx), 0.0f);
    float wy = fmaxf(__fsub_rn(rby, lty), 0.0f);
    float inter = __fmul_rn(wx, wy);
    float ag = __fmul_rn(__fsub_rn(g2, g0), __fsub_rn(g3, g1));
    float ap = __fmul_rn(__fsub_rn(p2, p0), __fsub_rn(p3, p1));
    float den = __fadd_rn(__fsub_rn(__fadd_rn(ag, ap), inter), EPS_F);
    float iou = __fdiv_rn(inter, den);
    if (iou > 1.0f) iou = 0.0f;            // (1.0 + 1e-9) rounds to 1.0f in f32
    iou = fminf(fmaxf(iou, 0.0f), 1.0f);
    return iou;
}

// Sortable key: (truncated double bits of s>=0) << 0 | (0xFFFF - l) in low 16.
// Larger key == (higher value, then lower anchor index). Keys are unique.
__device__ __forceinline__ unsigned long long make_key(double s, int l) {
    unsigned long long sb = (unsigned long long)__double_as_longlong(s);
    return (sb & 0xFFFFFFFFFFFF0000ull) | (unsigned long long)(0xFFFF - l);
}

// K1: one 1024-thread block per (gt n, batch b). Per-thread top-13 in
// registers (u64 keys, unrolled compare-swap insert — no runtime indexing),
// per-wave shuffle head-merge (no barriers), one __syncthreads, single-wave
// final merge of 16x13 survivors. Winner bits scattered via atomicOr.
__global__ __launch_bounds__(1024) void k_topk(
    const float* __restrict__ psc, const float* __restrict__ pbox,
    const float* __restrict__ pts, const int* __restrict__ glbl,
    const float* __restrict__ gbox, const float* __restrict__ gpad,
    unsigned long long* __restrict__ posbits)
{
    const int n = blockIdx.x, b = blockIdx.y, t = threadIdx.x;
    if (gpad[b * N_DIM + n] <= 0.0f) return;   // padded GT: uniform block exit

    const float g0 = gbox[(b * N_DIM + n) * 4 + 0];
    const float g1 = gbox[(b * N_DIM + n) * 4 + 1];
    const float g2 = gbox[(b * N_DIM + n) * 4 + 2];
    const float g3 = gbox[(b * N_DIM + n) * 4 + 3];
    int lbl = glbl[b * N_DIM + n];
    lbl = min(max(lbl, 0), C_DIM - 1);
    const float* psb = psc + (size_t)b * L_DIM * C_DIM;
    const float* pbb = pbox + (size_t)b * L_DIM * 4;

    // per-thread top-13, sorted desc, registers only
    unsigned long long key[K_TOP];
    #pragma unroll
    for (int k = 0; k < K_TOP; ++k) key[k] = 0ull;

    for (int l = t; l < L_DIM; l += 1024) {
        const float2 ap = reinterpret_cast<const float2*>(pts)[l];
        unsigned long long cand = (unsigned long long)(0xFFFF - l); // s == 0
        if (ap.x >= g0 && ap.x <= g2 && ap.y >= g1 && ap.y <= g3) {
            const float4 pbv = reinterpret_cast<const float4*>(pbb)[l];
            float iou = iou_pair(g0, g1, g2, g3, pbv.x, pbv.y, pbv.z, pbv.w);
            if (iou > 0.0f) {
                float cs = psb[(size_t)l * C_DIM + lbl];
                double d = (double)iou, d2 = d * d;
                cand = make_key((double)cs * (d2 * d2 * d2), l);
            }
        }
        if (cand > key[K_TOP - 1]) {
            #pragma unroll
            for (int k = 0; k < K_TOP; ++k) {
                unsigned long long hi = key[k] > cand ? key[k] : cand;
                unsigned long long lo = key[k] > cand ? cand : key[k];
                key[k] = hi; cand = lo;
            }
        }
    }

    // per-wave head-merge: 13 rounds of 64-lane butterfly argmax, no barriers
    const int lane = t & 63, wid = t >> 6;           // 16 waves
    __shared__ unsigned long long wl[16 * K_TOP];
    #pragma unroll 1
    for (int r = 0; r < K_TOP; ++r) {
        unsigned long long best = key[0];
        #pragma unroll
        for (int d = 1; d < 64; d <<= 1) {
            unsigned long long o = __shfl_xor(best, d, 64);
            best = o > best ? o : best;
        }
        if (key[0] == best) {                        // unique keys -> one winner
            #pragma unroll
            for (int k = 0; k < K_TOP - 1; ++k) key[k] = key[k + 1];
            key[K_TOP - 1] = 0ull;
        }
        if (lane == 0) wl[wid * K_TOP + r] = best;
    }
    __syncthreads();
    if (wid != 0) return;

    // single-wave merge of 208 survivors (4 per lane, sorted, head-merge)
    unsigned long long m0 = wl[lane];
    unsigned long long m1 = wl[lane + 64];
    unsigned long long m2 = wl[lane + 128];
    unsigned long long m3 = (lane + 192 < 16 * K_TOP) ? wl[lane + 192] : 0ull;
    #define CSWP(a, b) { unsigned long long hi = a > b ? a : b, lo = a > b ? b : a; a = hi; b = lo; }
    CSWP(m0, m1) CSWP(m2, m3) CSWP(m0, m2) CSWP(m1, m3) CSWP(m1, m2)
    #undef CSWP

    #pragma unroll 1
    for (int r = 0; r < K_TOP; ++r) {
        unsigned long long best = m0;
        #pragma unroll
        for (int d = 1; d < 64; d <<= 1) {
            unsigned long long o = __shfl_xor(best, d, 64);
            best = o > best ? o : best;
        }
        if (m0 == best) { m0 = m1; m1 = m2; m2 = m3; m3 = 0ull; }
        if (lane == 0) {
            int win = 0xFFFF - (int)(best & 0xFFFFull);
            atomicOr(&posbits[((size_t)b * L_DIM + win) * 2 + (n >> 6)],
                     1ULL << (n & 63));
        }
    }
}

// K2: one thread per anchor. Recompute 128 ious (GT boxes in LDS), build
// positive = topk_bit & spatial, resolve conflicts via best-iou argmax
// (first-max semantics), write labels/boxes, feed per-GT maxima atomics.
__global__ __launch_bounds__(256) void k_assign(
    const float* __restrict__ psc, const float* __restrict__ pbox,
    const float* __restrict__ pts, const int* __restrict__ glbl,
    const float* __restrict__ gbox,
    const unsigned long long* __restrict__ posbits,
    const int* __restrict__ bgp,
    float* __restrict__ out_lab, float* __restrict__ out_box,
    int* __restrict__ fin_out, float* __restrict__ alat,
    float* __restrict__ maxal, float* __restrict__ maxio)
{
    const int b = blockIdx.y, t = threadIdx.x;
    const int l = blockIdx.x * 256 + t;
    __shared__ float4 gb[N_DIM];
    __shared__ int    gl[N_DIM];
    if (t < N_DIM) {
        gb[t] = reinterpret_cast<const float4*>(gbox)[(size_t)b * N_DIM + t];
        gl[t] = glbl[b * N_DIM + t];
    }
    __syncthreads();
    if (l >= L_DIM) return;

    const size_t bl = (size_t)b * L_DIM + l;
    const float4 pb = reinterpret_cast<const float4*>(pbox)[bl];
    const float2 ap = reinterpret_cast<const float2*>(pts)[l];
    const unsigned long long w0 = posbits[bl * 2 + 0];
    const unsigned long long w1 = posbits[bl * 2 + 1];

    unsigned long long s0 = 0ull, s1 = 0ull;
    float best = -1.0f; int bestn = 0;
    for (int n = 0; n < N_DIM; ++n) {
        float4 g = gb[n];
        float iou = iou_pair(g.x, g.y, g.z, g.w, pb.x, pb.y, pb.z, pb.w);
        if (iou > best) { best = iou; bestn = n; }            // strict > = first-max
        if (ap.x >= g.x && ap.x <= g.z && ap.y >= g.y && ap.y <= g.w) {
            if (n < 64) s0 |= 1ull << n; else s1 |= 1ull << (n - 64);
        }
    }
    unsigned long long p0 = w0 & s0, p1 = w1 & s1;
    int cnt = __popcll(p0) + __popcll(p1);
    int fin;
    if (cnt == 0) fin = -1;
    else if (cnt == 1) fin = p0 ? (__ffsll(p0) - 1) : (64 + __ffsll(p1) - 1);
    else {
        bool posbest = (bestn < 64) ? ((p0 >> bestn) & 1ull) : ((p1 >> (bestn - 64)) & 1ull);
        fin = posbest ? bestn : -1;
    }

    out_lab[bl] = (fin >= 0) ? (float)gl[fin] : (float)bgp[0];
    int gidx = (fin >= 0) ? fin : 0;              // ref gathers boxes with argmax=0 for bg
    reinterpret_cast<float4*>(out_box)[bl] = gb[gidx];
    fin_out[bl] = fin;

    if (fin >= 0) {
        float4 g = gb[fin];
        float iou = iou_pair(g.x, g.y, g.z, g.w, pb.x, pb.y, pb.z, pb.w);
        int lb = min(max(gl[fin], 0), C_DIM - 1);
        float cs = psc[bl * C_DIM + lb];
        float al = cs * powf(iou, 6.0f);
        alat[bl] = al;
        // all values >= 0, init 0 -> int-compare == float-compare
        atomicMax((int*)&maxal[b * N_DIM + fin], __float_as_int(al));
        atomicMax((int*)&maxio[b * N_DIM + fin], __float_as_int(iou));
    }
}

// K3a: per-anchor norm factor + assigned class (-1 = background).
__global__ __launch_bounds__(256) void k_norm(
    const int* __restrict__ fin_out, const float* __restrict__ alat,
    const float* __restrict__ maxal, const float* __restrict__ maxio,
    const int* __restrict__ glbl,
    float* __restrict__ nf, int* __restrict__ cls)
{
    int i = blockIdx.x * 256 + threadIdx.x;
    if (i >= B_DIM * L_DIM) return;
    int b = i / L_DIM;
    int fin = fin_out[i];
    float v = 0.0f; int c = -1;
    if (fin >= 0) {
        v = alat[i] / (maxal[b * N_DIM + fin] + EPS_F) * maxio[b * N_DIM + fin];
        c = glbl[b * N_DIM + fin];
    }
    nf[i] = v; cls[i] = c;
}

// K3: fill the one-hot-scaled scores, float4-vectorized (C=80 divisible by 4).
__global__ __launch_bounds__(256) void k_scores(
    const float* __restrict__ nf, const int* __restrict__ cls,
    float* __restrict__ outs)
{
    const int TOT4 = B_DIM * L_DIM * C_DIM / 4;
    int q = blockIdx.x * 256 + threadIdx.x;
    if (q >= TOT4) return;
    int idx = q * 4;
    int a = idx / C_DIM;
    int c0 = idx - a * C_DIM;
    int cl = cls[a];
    float v = nf[a];
    float4 o;
    o.x = (c0 + 0 == cl) ? v : 0.0f;
    o.y = (c0 + 1 == cl) ? v : 0.0f;
    o.z = (c0 + 2 == cl) ? v : 0.0f;
    o.w = (c0 + 3 == cl) ? v : 0.0f;
    reinterpret_cast<float4*>(outs)[q] = o;
}

extern "C" void kernel_launch(void* const* d_in, const int* in_sizes, int n_in,
                              void* d_out, int out_size, void* d_ws, size_t ws_size,
                              hipStream_t stream)
{
    const float* psc  = (const float*)d_in[0];   // [B,L,C]
    const float* pbox = (const float*)d_in[1];   // [B,L,4]
    const float* pts  = (const float*)d_in[2];   // [1,L,2]
    const int*   glbl = (const int*)d_in[3];     // [B,N,1]
    const float* gbox = (const float*)d_in[4];   // [B,N,4]
    const float* gpad = (const float*)d_in[5];   // [B,N,1]
    const int*   bgp  = (const int*)d_in[6];     // scalar (=C)

    // workspace layout (8-byte aligned blocks)
    const size_t POSB_BYTES = (size_t)B_DIM * L_DIM * 2 * sizeof(unsigned long long); // 4,300,800
    char* w = (char*)d_ws;
    unsigned long long* posbits = (unsigned long long*)w;
    float* maxal = (float*)(w + POSB_BYTES);                                   // 4096 B
    float* maxio = (float*)(w + POSB_BYTES + 4096);                            // 4096 B
    int*   fin   = (int*)  (w + POSB_BYTES + 8192);                            // 1,075,200 B
    float* alat  = (float*)(w + POSB_BYTES + 8192 + 1075200);
    float* nf    = (float*)(w + POSB_BYTES + 8192 + 2 * 1075200);
    int*   cls   = (int*)  (w + POSB_BYTES + 8192 + 3 * 1075200);

    // zero the accumulated regions (posbits + maxal + maxio) every call
    hipMemsetAsync(d_ws, 0, POSB_BYTES + 8192, stream);

    float* out_lab = (float*)d_out;                              // [B,L]
    float* out_box = out_lab + (size_t)B_DIM * L_DIM;            // [B,L,4]
    float* out_sc  = out_box + (size_t)B_DIM * L_DIM * 4;        // [B,L,C]

    k_topk<<<dim3(N_DIM, B_DIM), dim3(1024), 0, stream>>>(psc, pbox, pts, glbl, gbox, gpad, posbits);
    k_assign<<<dim3((L_DIM + 255) / 256, B_DIM), dim3(256), 0, stream>>>(
        psc, pbox, pts, glbl, gbox, posbits, bgp,
        out_lab, out_box, fin, alat, maxal, maxio);
    k_norm<<<dim3((B_DIM * L_DIM + 255) / 256), dim3(256), 0, stream>>>(
        fin, alat, maxal, maxio, glbl, nf, cls);
    k_scores<<<dim3((B_DIM * L_DIM * C_DIM / 4 + 255) / 256), dim3(256), 0, stream>>>(
        nf, cls, out_sc);
}

// Round 3
// 147.053 us; speedup vs baseline: 1.9065x; 1.4995x over previous
//
#include <hip/hip_runtime.h>
#include <cstdint>
#include <cstddef>

#define B_DIM 8
#define L_DIM 33600
#define N_DIM 128
#define C_DIM 80
#define K_TOP 13
#define EPS_F 1e-9f
#define CAND_CAP 8192   // >3x the max plausible inside-count (~2600)

// Bit-exact replica of the reference IoU (f32, no FMA contraction, same op order).
__device__ __forceinline__ float iou_pair(float g0, float g1, float g2, float g3,
                                          float p0, float p1, float p2, float p3) {
    float ltx = fmaxf(g0, p0), lty = fmaxf(g1, p1);
    float rbx = fminf(g2, p2), rby = fminf(g3, p3);
    float wx = fmaxf(__fsub_rn(rbx, ltx), 0.0f);
    float wy = fmaxf(__fsub_rn(rby, lty), 0.0f);
    float inter = __fmul_rn(wx, wy);
    float ag = __fmul_rn(__fsub_rn(g2, g0), __fsub_rn(g3, g1));
    float ap = __fmul_rn(__fsub_rn(p2, p0), __fsub_rn(p3, p1));
    float den = __fadd_rn(__fsub_rn(__fadd_rn(ag, ap), inter), EPS_F);
    float iou = __fdiv_rn(inter, den);
    if (iou > 1.0f) iou = 0.0f;            // (1.0 + 1e-9) rounds to 1.0f in f32
    iou = fminf(fmaxf(iou, 0.0f), 1.0f);
    return iou;
}

// Sortable key: (truncated double bits of s>=0) | (0xFFFF - l) in low 16.
// Larger key == (higher value, then lower anchor index). Keys are unique.
__device__ __forceinline__ unsigned long long make_key(double s, int l) {
    unsigned long long sb = (unsigned long long)__double_as_longlong(s);
    return (sb & 0xFFFFFFFFFFFF0000ull) | (unsigned long long)(0xFFFF - l);
}

// K1: one 1024-thread block per (gt n, batch b).
// Phase 1: compact spatially-inside anchors (l>=32) to LDS via ballot append;
//          l=0..31 always seeded (exact zero-fill semantics for <13 positives).
// Phase 2: score only the ~700 candidates; per-thread 8-deep sorted reg list.
// Phase 3: per-wave 13-round shuffle head-merge, one barrier, single-wave
//          final merge of 16x13 heads; winner bits scattered via atomicOr.
__global__ __launch_bounds__(1024) void k_topk(
    const float* __restrict__ psc, const float* __restrict__ pbox,
    const float* __restrict__ pts, const int* __restrict__ glbl,
    const float* __restrict__ gbox, const float* __restrict__ gpad,
    unsigned long long* __restrict__ posbits)
{
    const int n = blockIdx.x, b = blockIdx.y, t = threadIdx.x;
    if (gpad[b * N_DIM + n] <= 0.0f) return;   // padded GT: uniform block exit

    const float g0 = gbox[(b * N_DIM + n) * 4 + 0];
    const float g1 = gbox[(b * N_DIM + n) * 4 + 1];
    const float g2 = gbox[(b * N_DIM + n) * 4 + 2];
    const float g3 = gbox[(b * N_DIM + n) * 4 + 3];
    int lbl = glbl[b * N_DIM + n];
    lbl = min(max(lbl, 0), C_DIM - 1);
    const float* psb = psc + (size_t)b * L_DIM * C_DIM;
    const float* pbb = pbox + (size_t)b * L_DIM * 4;

    __shared__ unsigned int cand[CAND_CAP];
    __shared__ int cnt;
    __shared__ unsigned long long wl[16 * K_TOP];
    if (t == 0) cnt = 32;
    if (t < 32) cand[t] = t;                   // unconditional zero-fill seeds
    __syncthreads();

    const int lane = t & 63, wid = t >> 6;     // 16 waves

    // ---- Phase 1: containment-only compaction (no iou, no gather) ----
    for (int base_l = 0; base_l < L_DIM; base_l += 1024) {
        int l = base_l + t;
        bool pred = false;
        if (l >= 32 && l < L_DIM) {
            const float2 ap = reinterpret_cast<const float2*>(pts)[l];
            pred = (ap.x >= g0 && ap.x <= g2 && ap.y >= g1 && ap.y <= g3);
        }
        unsigned long long m = __ballot(pred);
        if (m) {
            int leader = __ffsll((long long)m) - 1;
            int basep = 0;
            if (lane == leader) basep = atomicAdd(&cnt, __popcll(m));
            basep = __shfl(basep, leader, 64);
            if (pred) {
                int pos = basep + __popcll(m & ((1ull << lane) - 1ull));
                if (pos < CAND_CAP) cand[pos] = (unsigned int)l;
            }
        }
    }
    __syncthreads();
    const int nc = min(cnt, CAND_CAP);

    // ---- Phase 2: score candidates, per-thread sorted list (8 deep) ----
    unsigned long long key[8];
    #pragma unroll
    for (int k = 0; k < 8; ++k) key[k] = 0ull;
    for (int i = t; i < nc; i += 1024) {
        const int l = (int)cand[i];
        const float2 ap = reinterpret_cast<const float2*>(pts)[l];
        unsigned long long ck = (unsigned long long)(0xFFFF - l);  // s == 0
        if (ap.x >= g0 && ap.x <= g2 && ap.y >= g1 && ap.y <= g3) {
            const float4 pbv = reinterpret_cast<const float4*>(pbb)[l];
            float iou = iou_pair(g0, g1, g2, g3, pbv.x, pbv.y, pbv.z, pbv.w);
            if (iou > 0.0f) {
                float cs = psb[(size_t)l * C_DIM + lbl];
                double d = (double)iou, d2 = d * d;
                ck = make_key((double)cs * (d2 * d2 * d2), l);
            }
        }
        #pragma unroll
        for (int k = 0; k < 8; ++k) {          // bubble insert, static indices
            unsigned long long hi = key[k] > ck ? key[k] : ck;
            unsigned long long lo = key[k] > ck ? ck : key[k];
            key[k] = hi; ck = lo;
        }
    }

    // ---- Phase 3a: per-wave head-merge, no barriers ----
    #pragma unroll 1
    for (int r = 0; r < K_TOP; ++r) {
        unsigned long long best = key[0];
        #pragma unroll
        for (int d = 1; d < 64; d <<= 1) {
            unsigned long long o = __shfl_xor(best, d, 64);
            best = o > best ? o : best;
        }
        if (key[0] == best && best != 0ull) {  // unique keys -> one winner
            #pragma unroll
            for (int k = 0; k < 7; ++k) key[k] = key[k + 1];
            key[7] = 0ull;
        }
        if (lane == 0) wl[wid * K_TOP + r] = best;
    }
    __syncthreads();
    if (wid != 0) return;

    // ---- Phase 3b: single-wave merge of 208 heads (4/lane, sorted) ----
    unsigned long long m0 = wl[lane];
    unsigned long long m1 = wl[lane + 64];
    unsigned long long m2 = wl[lane + 128];
    unsigned long long m3 = (lane + 192 < 16 * K_TOP) ? wl[lane + 192] : 0ull;
    #define CSWP(a, b) { unsigned long long hi = a > b ? a : b, lo = a > b ? b : a; a = hi; b = lo; }
    CSWP(m0, m1) CSWP(m2, m3) CSWP(m0, m2) CSWP(m1, m3) CSWP(m1, m2)
    #undef CSWP

    #pragma unroll 1
    for (int r = 0; r < K_TOP; ++r) {
        unsigned long long best = m0;
        #pragma unroll
        for (int d = 1; d < 64; d <<= 1) {
            unsigned long long o = __shfl_xor(best, d, 64);
            best = o > best ? o : best;
        }
        if (m0 == best) { m0 = m1; m1 = m2; m2 = m3; m3 = 0ull; }
        if (lane == 0) {
            int win = 0xFFFF - (int)(best & 0xFFFFull);
            atomicOr(&posbits[((size_t)b * L_DIM + win) * 2 + (n >> 6)],
                     1ULL << (n & 63));
        }
    }
}

// K2: one thread per anchor. Recompute 128 ious (GT boxes in LDS), build
// positive = topk_bit & spatial, resolve conflicts via best-iou argmax
// (first-max semantics), write labels/boxes, feed per-GT maxima atomics.
__global__ __launch_bounds__(256) void k_assign(
    const float* __restrict__ psc, const float* __restrict__ pbox,
    const float* __restrict__ pts, const int* __restrict__ glbl,
    const float* __restrict__ gbox,
    const unsigned long long* __restrict__ posbits,
    const int* __restrict__ bgp,
    float* __restrict__ out_lab, float* __restrict__ out_box,
    int* __restrict__ fin_out, float* __restrict__ alat,
    float* __restrict__ maxal, float* __restrict__ maxio)
{
    const int b = blockIdx.y, t = threadIdx.x;
    const int l = blockIdx.x * 256 + t;
    __shared__ float4 gb[N_DIM];
    __shared__ int    gl[N_DIM];
    if (t < N_DIM) {
        gb[t] = reinterpret_cast<const float4*>(gbox)[(size_t)b * N_DIM + t];
        gl[t] = glbl[b * N_DIM + t];
    }
    __syncthreads();
    if (l >= L_DIM) return;

    const size_t bl = (size_t)b * L_DIM + l;
    const float4 pb = reinterpret_cast<const float4*>(pbox)[bl];
    const float2 ap = reinterpret_cast<const float2*>(pts)[l];
    const unsigned long long w0 = posbits[bl * 2 + 0];
    const unsigned long long w1 = posbits[bl * 2 + 1];

    unsigned long long s0 = 0ull, s1 = 0ull;
    float best = -1.0f; int bestn = 0;
    for (int n = 0; n < N_DIM; ++n) {
        float4 g = gb[n];
        float iou = iou_pair(g.x, g.y, g.z, g.w, pb.x, pb.y, pb.z, pb.w);
        if (iou > best) { best = iou; bestn = n; }            // strict > = first-max
        if (ap.x >= g.x && ap.x <= g.z && ap.y >= g.y && ap.y <= g.w) {
            if (n < 64) s0 |= 1ull << n; else s1 |= 1ull << (n - 64);
        }
    }
    unsigned long long p0 = w0 & s0, p1 = w1 & s1;
    int cnt = __popcll(p0) + __popcll(p1);
    int fin;
    if (cnt == 0) fin = -1;
    else if (cnt == 1) fin = p0 ? (__ffsll(p0) - 1) : (64 + __ffsll(p1) - 1);
    else {
        bool posbest = (bestn < 64) ? ((p0 >> bestn) & 1ull) : ((p1 >> (bestn - 64)) & 1ull);
        fin = posbest ? bestn : -1;
    }

    out_lab[bl] = (fin >= 0) ? (float)gl[fin] : (float)bgp[0];
    int gidx = (fin >= 0) ? fin : 0;              // ref gathers boxes with argmax=0 for bg
    reinterpret_cast<float4*>(out_box)[bl] = gb[gidx];
    fin_out[bl] = fin;

    if (fin >= 0) {
        float4 g = gb[fin];
        float iou = iou_pair(g.x, g.y, g.z, g.w, pb.x, pb.y, pb.z, pb.w);
        int lb = min(max(gl[fin], 0), C_DIM - 1);
        float cs = psc[bl * C_DIM + lb];
        float al = cs * powf(iou, 6.0f);
        alat[bl] = al;
        // all values >= 0, init 0 -> int-compare == float-compare
        atomicMax((int*)&maxal[b * N_DIM + fin], __float_as_int(al));
        atomicMax((int*)&maxio[b * N_DIM + fin], __float_as_int(iou));
    }
}

// K3a: per-anchor norm factor + assigned class (-1 = background).
__global__ __launch_bounds__(256) void k_norm(
    const int* __restrict__ fin_out, const float* __restrict__ alat,
    const float* __restrict__ maxal, const float* __restrict__ maxio,
    const int* __restrict__ glbl,
    float* __restrict__ nf, int* __restrict__ cls)
{
    int i = blockIdx.x * 256 + threadIdx.x;
    if (i >= B_DIM * L_DIM) return;
    int b = i / L_DIM;
    int fin = fin_out[i];
    float v = 0.0f; int c = -1;
    if (fin >= 0) {
        v = alat[i] / (maxal[b * N_DIM + fin] + EPS_F) * maxio[b * N_DIM + fin];
        c = glbl[b * N_DIM + fin];
    }
    nf[i] = v; cls[i] = c;
}

// K3: fill the one-hot-scaled scores, float4-vectorized (C=80 divisible by 4).
__global__ __launch_bounds__(256) void k_scores(
    const float* __restrict__ nf, const int* __restrict__ cls,
    float* __restrict__ outs)
{
    const int TOT4 = B_DIM * L_DIM * C_DIM / 4;
    int q = blockIdx.x * 256 + threadIdx.x;
    if (q >= TOT4) return;
    int idx = q * 4;
    int a = idx / C_DIM;
    int c0 = idx - a * C_DIM;
    int cl = cls[a];
    float v = nf[a];
    float4 o;
    o.x = (c0 + 0 == cl) ? v : 0.0f;
    o.y = (c0 + 1 == cl) ? v : 0.0f;
    o.z = (c0 + 2 == cl) ? v : 0.0f;
    o.w = (c0 + 3 == cl) ? v : 0.0f;
    reinterpret_cast<float4*>(outs)[q] = o;
}

extern "C" void kernel_launch(void* const* d_in, const int* in_sizes, int n_in,
                              void* d_out, int out_size, void* d_ws, size_t ws_size,
                              hipStream_t stream)
{
    const float* psc  = (const float*)d_in[0];   // [B,L,C]
    const float* pbox = (const float*)d_in[1];   // [B,L,4]
    const float* pts  = (const float*)d_in[2];   // [1,L,2]
    const int*   glbl = (const int*)d_in[3];     // [B,N,1]
    const float* gbox = (const float*)d_in[4];   // [B,N,4]
    const float* gpad = (const float*)d_in[5];   // [B,N,1]
    const int*   bgp  = (const int*)d_in[6];     // scalar (=C)

    // workspace layout (8-byte aligned blocks)
    const size_t POSB_BYTES = (size_t)B_DIM * L_DIM * 2 * sizeof(unsigned long long); // 4,300,800
    char* w = (char*)d_ws;
    unsigned long long* posbits = (unsigned long long*)w;
    float* maxal = (float*)(w + POSB_BYTES);                                   // 4096 B
    float* maxio = (float*)(w + POSB_BYTES + 4096);                            // 4096 B
    int*   fin   = (int*)  (w + POSB_BYTES + 8192);                            // 1,075,200 B
    float* alat  = (float*)(w + POSB_BYTES + 8192 + 1075200);
    float* nf    = (float*)(w + POSB_BYTES + 8192 + 2 * 1075200);
    int*   cls   = (int*)  (w + POSB_BYTES + 8192 + 3 * 1075200);

    // zero the accumulated regions (posbits + maxal + maxio) every call
    hipMemsetAsync(d_ws, 0, POSB_BYTES + 8192, stream);

    float* out_lab = (float*)d_out;                              // [B,L]
    float* out_box = out_lab + (size_t)B_DIM * L_DIM;            // [B,L,4]
    float* out_sc  = out_box + (size_t)B_DIM * L_DIM * 4;        // [B,L,C]

    k_topk<<<dim3(N_DIM, B_DIM), dim3(1024), 0, stream>>>(psc, pbox, pts, glbl, gbox, gpad, posbits);
    k_assign<<<dim3((L_DIM + 255) / 256, B_DIM), dim3(256), 0, stream>>>(
        psc, pbox, pts, glbl, gbox, posbits, bgp,
        out_lab, out_box, fin, alat, maxal, maxio);
    k_norm<<<dim3((B_DIM * L_DIM + 255) / 256), dim3(256), 0, stream>>>(
        fin, alat, maxal, maxio, glbl, nf, cls);
    k_scores<<<dim3((B_DIM * L_DIM * C_DIM / 4 + 255) / 256), dim3(256), 0, stream>>>(
        nf, cls, out_sc);
}